// Round 14
// baseline (109.857 us; speedup 1.0000x reference)
//
#include <hip/hip_runtime.h>
#include <hip/hip_bf16.h>
#include <math.h>

#define T_LEN   7680
#define NSEG    59
#define NBINS   45
#define NTHR    512    // 8 waves; each wave owns one channel
#define NBLK    512    // 512 blocks x 8 waves = 4096 channels; 2 blocks/CU

using bf16x8 = __attribute__((ext_vector_type(8))) short;
using f32x4  = __attribute__((ext_vector_type(4))) float;

__device__ __forceinline__ unsigned f2bf(float f) {
    unsigned u = __builtin_bit_cast(unsigned, f);
    return (u + 0x7FFFu + ((u >> 16) & 1u)) >> 16;   // RNE fp32->bf16
}

// mt_lds swizzle (R12-proven): rows stride 512 B -> mix bits 9-11 into 4-6.
__device__ __forceinline__ unsigned physB(unsigned a) {
    return a ^ (((a >> 9) & 7u) << 4);
}

// Basis table mt[96][256] bf16 (detrend+window folded; R2-proven math):
//   col j=2i: w_n*cos(2pi(i+1)n/256); col j=2i+1: -w_n*sin(...);
//   col 0 adds +0.25 (exact detrend correction for k=1 real part).
//   Rows 90..95 zero (read by dummy cols of tile 5; outputs skipped).
__global__ void build_basis_kernel(unsigned short* __restrict__ mt) {
    int j = blockIdx.x, n = threadIdx.x;
    const float TH = 0.02454369260617026f;           // 2*pi/256
    float w = 0.5f - 0.5f * cosf((float)n * TH);     // periodic hann
    float v = 0.f;
    if (j < 90) {
        int k = (j >> 1) + 1;
        int m = (k * n) & 255;                       // exact periodic reduction
        float th = (float)m * TH;
        v = (j & 1) ? (-w * sinf(th)) : (w * cosf(th));
        if (j == 0) v += 0.25f;                      // fold detrend into k=1 re
    }
    mt[j * 256 + n] = (unsigned short)f2bf(v);
}

// Wave-private channels (R13 structure, B-address FIXED):
//  R13 bug: XOR applied to bbase BEFORE adding k0*64 -> carry corruption on
//  cols with j&4 at odd k0 (XOR bits 4-6 overlap add bits 6-8). Fix: XOR
//  LAST, after all adds (R12's exact formula). The addends j*512 / k0*64 /
//  q*16 occupy disjoint bit ranges -> sum is exact concatenation.
//  Ledger: no MFMA guards (R3-R5), no breg hoist (R7-R11), B via ds_read,
//  junk rows 59..63 via address clamp + square-sum mask.
__global__ __launch_bounds__(NTHR, 4)
void welch_main_kernel(const float* __restrict__ x,
                       const unsigned short* __restrict__ mt,
                       float* __restrict__ out) {
    __shared__ __align__(16) unsigned short mt_lds[96 * 256];  // 49152 B

    const int tid  = threadIdx.x;
    const int lane = tid & 63;
    const int w    = tid >> 6;

    // ---- stage mt (96 rows = 3072 x 16B = 6*512), physB-swizzled
    {
        const uint4* mt4 = reinterpret_cast<const uint4*>(mt);
        #pragma unroll
        for (int i = 0; i < 6; ++i) {
            int c = i * NTHR + tid;
            uint4 v = mt4[c];
            *reinterpret_cast<uint4*>((char*)mt_lds + physB((unsigned)c * 16u)) = v;
        }
    }
    __syncthreads();   // the only barrier in the kernel

    const int ch = blockIdx.x * 8 + w;
    const float* gx = x + (size_t)ch * T_LEN;
    const int col0 = lane & 15;
    const int q    = lane >> 4;

    // B addressing: col j = ct*16+col0. Keep base (j*512 + q*16) and swizzle
    // separate; XOR applied AFTER adding k0*64 at each read.
    unsigned bbase0[6], bswz[6];
    #pragma unroll
    for (int ct = 0; ct < 6; ++ct) {
        int j = ct * 16 + col0;
        bbase0[ct] = (unsigned)(j * 512 + q * 16);
        bswz[ct]   = (unsigned)((j & 7) << 4);
    }

    float p[6] = {0.f, 0.f, 0.f, 0.f, 0.f, 0.f};

    #pragma unroll
    for (int rt = 0; rt < 4; ++rt) {
        const int row     = rt * 16 + col0;
        const int row_eff = row > 58 ? 58 : row;       // clamp: junk rows read
        const float* rowp = gx + row_eff * 128 + q * 8; // row-58 data (masked)

        f32x4 acc[6];
        #pragma unroll
        for (int ct = 0; ct < 6; ++ct) acc[ct] = (f32x4){0.f, 0.f, 0.f, 0.f};

        #pragma unroll
        for (int k0 = 0; k0 < 8; ++k0) {
            f32x4 x0 = *reinterpret_cast<const f32x4*>(rowp + k0 * 32);
            f32x4 x1 = *reinterpret_cast<const f32x4*>(rowp + k0 * 32 + 4);
            unsigned d0 = f2bf(x0[0]) | (f2bf(x0[1]) << 16);
            unsigned d1 = f2bf(x0[2]) | (f2bf(x0[3]) << 16);
            unsigned d2 = f2bf(x1[0]) | (f2bf(x1[1]) << 16);
            unsigned d3 = f2bf(x1[2]) | (f2bf(x1[3]) << 16);
            uint4 pk = {d0, d1, d2, d3};
            bf16x8 a = __builtin_bit_cast(bf16x8, pk);
            #pragma unroll
            for (int ct = 0; ct < 6; ++ct) {
                bf16x8 b = *reinterpret_cast<const bf16x8*>(
                    (char*)mt_lds + ((bbase0[ct] + (unsigned)k0 * 64u) ^ bswz[ct]));
                acc[ct] = __builtin_amdgcn_mfma_f32_16x16x32_bf16(a, b, acc[ct], 0, 0, 0);
            }
        }

        // square-sum fold; C/D layout: col=lane&15, row=rt*16 + q*4 + r.
        const int rowbase = rt * 16 + q * 4;
        #pragma unroll
        for (int ct = 0; ct < 6; ++ct) {
            float s = 0.f;
            #pragma unroll
            for (int r = 0; r < 4; ++r)
                if (rowbase + r < NSEG) s += acc[ct][r] * acc[ct][r];
            p[ct] += s;
        }
    }

    // ---- wave-local reduction + output (45 bins for this wave's channel)
    const float CNORM = 2.0f / (24576.0f * 59.0f);     // fs*sum(w^2) = 256*96
    #pragma unroll
    for (int ct = 0; ct < 6; ++ct) {
        float v = p[ct];
        v += __shfl_xor(v, 16);
        v += __shfl_xor(v, 32);    // col total (sum over all row-groups)
        v += __shfl_xor(v, 1);     // re^2 + im^2 (col pair)
        int bin = ct * 8 + (col0 >> 1);
        if (lane < 16 && (lane & 1) == 0 && bin < NBINS)
            out[(size_t)ch * NBINS + bin] = log1pf(v * CNORM);
    }
}

extern "C" void kernel_launch(void* const* d_in, const int* in_sizes, int n_in,
                              void* d_out, int out_size, void* d_ws, size_t ws_size,
                              hipStream_t stream) {
    const float* x = (const float*)d_in[0];
    float* out = (float*)d_out;
    unsigned short* mt = (unsigned short*)d_ws;   // 96*256*2 = 49152 B

    build_basis_kernel<<<96, 256, 0, stream>>>(mt);
    welch_main_kernel<<<NBLK, NTHR, 0, stream>>>(x, mt, out);
}

// Round 15
// 47.465 us; speedup vs baseline: 2.3145x; 2.3145x over previous
//
#include <hip/hip_runtime.h>
#include <hip/hip_bf16.h>
#include <math.h>

#define T_LEN   7680
#define NSEG    59
#define NBINS   45
#define NTHR    512    // 8 waves; each wave owns one channel
#define NBLK    512    // 512 blocks x 8 waves = 4096 channels

using bf16x8 = __attribute__((ext_vector_type(8))) short;
using f32x4  = __attribute__((ext_vector_type(4))) float;

__device__ __forceinline__ unsigned f2bf(float f) {
    unsigned u = __builtin_bit_cast(unsigned, f);
    return (u + 0x7FFFu + ((u >> 16) & 1u)) >> 16;   // RNE fp32->bf16
}

// mt_lds swizzle (R12/R14-proven): rows stride 512 B -> mix bits 9-11 into 4-6.
__device__ __forceinline__ unsigned physB(unsigned a) {
    return a ^ (((a >> 9) & 7u) << 4);
}

// Basis table mt[96][256] bf16 (detrend+window folded; R2-proven math):
//   col j=2i: w_n*cos(2pi(i+1)n/256); col j=2i+1: -w_n*sin(...);
//   col 0 adds +0.25 (exact detrend correction for k=1 real part).
//   Rows 90..95 zero (read by dummy cols of tile 5; outputs skipped).
__global__ void build_basis_kernel(unsigned short* __restrict__ mt) {
    int j = blockIdx.x, n = threadIdx.x;
    const float TH = 0.02454369260617026f;           // 2*pi/256
    float w = 0.5f - 0.5f * cosf((float)n * TH);     // periodic hann
    float v = 0.f;
    if (j < 90) {
        int k = (j >> 1) + 1;
        int m = (k * n) & 255;                       // exact periodic reduction
        float th = (float)m * TH;
        v = (j & 1) ? (-w * sinf(th)) : (w * cosf(th));
        if (j == 0) v += 0.25f;                      // fold detrend into k=1 re
    }
    mt[j * 256 + n] = (unsigned short)f2bf(v);
}

// Wave-private channels, REGISTER-DIETED to fit the allocator's 64-reg budget
// (R14: full k0 unroll hoisted 16 f32x4 loads -> 64-reg demand spike -> 202MB
// scratch spills at the compiler-chosen 64 cap -> 110us).
//  - #pragma unroll 1 on k0: only 2 f32x4 loads in flight (8 regs). Latency
//    covered by TLP (24 waves/CU) + L1 (rt working set 8KB: row r's k>=128
//    half == row r+1's k<128 half).
//  - address arrays gone: b0 + ct*8192 + k0*64 (disjoint bit ranges), XOR
//    LAST with swz=(col0&7)<<4  [j&7 == col0&7 since ct*16 = 0 mod 8].
//  - Census: acc24 + p6 + loads8 + a4 + b4 + misc10 ~= 56 < 64.
// Ledger: no MFMA guards (R3-R5), no breg hoist (R7-R11), B via ds_read,
// junk rows 59..63 via address clamp + square-sum mask (R14-proven).
__global__ __launch_bounds__(NTHR, 4)
void welch_main_kernel(const float* __restrict__ x,
                       const unsigned short* __restrict__ mt,
                       float* __restrict__ out) {
    __shared__ __align__(16) unsigned short mt_lds[96 * 256];  // 49152 B

    const int tid  = threadIdx.x;
    const int lane = tid & 63;
    const int w    = tid >> 6;

    // ---- stage mt (3072 x 16B = 6*512), physB-swizzled
    {
        const uint4* mt4 = reinterpret_cast<const uint4*>(mt);
        #pragma unroll
        for (int i = 0; i < 6; ++i) {
            int c = i * NTHR + tid;
            uint4 v = mt4[c];
            *reinterpret_cast<uint4*>((char*)mt_lds + physB((unsigned)c * 16u)) = v;
        }
    }
    __syncthreads();   // the only barrier in the kernel

    const int ch = blockIdx.x * 8 + w;
    const float* gx = x + (size_t)ch * T_LEN;
    const int col0 = lane & 15;
    const int q    = lane >> 4;

    const unsigned b0  = (unsigned)(col0 * 512 + q * 16);
    const unsigned swz = (unsigned)((col0 & 7) << 4);

    float p[6] = {0.f, 0.f, 0.f, 0.f, 0.f, 0.f};

    #pragma unroll
    for (int rt = 0; rt < 4; ++rt) {
        const int row     = rt * 16 + col0;
        const int row_eff = row > 58 ? 58 : row;        // clamp: junk rows
        const float* rowp = gx + row_eff * 128 + q * 8;

        f32x4 acc[6];
        #pragma unroll
        for (int ct = 0; ct < 6; ++ct) acc[ct] = (f32x4){0.f, 0.f, 0.f, 0.f};

        #pragma unroll 1
        for (int k0 = 0; k0 < 8; ++k0) {
            f32x4 x0 = *reinterpret_cast<const f32x4*>(rowp + k0 * 32);
            f32x4 x1 = *reinterpret_cast<const f32x4*>(rowp + k0 * 32 + 4);
            unsigned d0 = f2bf(x0[0]) | (f2bf(x0[1]) << 16);
            unsigned d1 = f2bf(x0[2]) | (f2bf(x0[3]) << 16);
            unsigned d2 = f2bf(x1[0]) | (f2bf(x1[1]) << 16);
            unsigned d3 = f2bf(x1[2]) | (f2bf(x1[3]) << 16);
            uint4 pk = {d0, d1, d2, d3};
            bf16x8 a = __builtin_bit_cast(bf16x8, pk);
            const unsigned koff = b0 + (unsigned)(k0 * 64);
            #pragma unroll
            for (int ct = 0; ct < 6; ++ct) {
                bf16x8 b = *reinterpret_cast<const bf16x8*>(
                    (char*)mt_lds + ((koff + (unsigned)(ct * 8192)) ^ swz));
                acc[ct] = __builtin_amdgcn_mfma_f32_16x16x32_bf16(a, b, acc[ct], 0, 0, 0);
            }
        }

        // square-sum fold; C/D layout: col=lane&15, row=rt*16 + q*4 + r.
        const int rowbase = rt * 16 + q * 4;
        #pragma unroll
        for (int ct = 0; ct < 6; ++ct) {
            float s = 0.f;
            #pragma unroll
            for (int r = 0; r < 4; ++r)
                if (rowbase + r < NSEG) s += acc[ct][r] * acc[ct][r];
            p[ct] += s;
        }
    }

    // ---- wave-local reduction + output (45 bins for this wave's channel)
    const float CNORM = 2.0f / (24576.0f * 59.0f);     // fs*sum(w^2) = 256*96
    #pragma unroll
    for (int ct = 0; ct < 6; ++ct) {
        float v = p[ct];
        v += __shfl_xor(v, 16);
        v += __shfl_xor(v, 32);    // col total (sum over all row-groups)
        v += __shfl_xor(v, 1);     // re^2 + im^2 (col pair)
        int bin = ct * 8 + (col0 >> 1);
        if (lane < 16 && (lane & 1) == 0 && bin < NBINS)
            out[(size_t)ch * NBINS + bin] = log1pf(v * CNORM);
    }
}

extern "C" void kernel_launch(void* const* d_in, const int* in_sizes, int n_in,
                              void* d_out, int out_size, void* d_ws, size_t ws_size,
                              hipStream_t stream) {
    const float* x = (const float*)d_in[0];
    float* out = (float*)d_out;
    unsigned short* mt = (unsigned short*)d_ws;   // 96*256*2 = 49152 B

    build_basis_kernel<<<96, 256, 0, stream>>>(mt);
    welch_main_kernel<<<NBLK, NTHR, 0, stream>>>(x, mt, out);
}

// Round 16
// 47.457 us; speedup vs baseline: 2.3149x; 1.0002x over previous
//
#include <hip/hip_runtime.h>
#include <hip/hip_bf16.h>
#include <math.h>

#define T_LEN   7680
#define NSEG    59
#define NBINS   45
#define NTHR    512    // 8 waves; each wave owns one channel
#define NBLK    512    // 512 blocks x 8 waves = 4096 channels

using bf16x8 = __attribute__((ext_vector_type(8))) short;
using f32x4  = __attribute__((ext_vector_type(4))) float;

__device__ __forceinline__ unsigned f2bf(float f) {
    unsigned u = __builtin_bit_cast(unsigned, f);
    return (u + 0x7FFFu + ((u >> 16) & 1u)) >> 16;   // RNE fp32->bf16
}

// mt_lds swizzle (R12/R14-proven): rows stride 512 B -> mix bits 9-11 into 4-6.
__device__ __forceinline__ unsigned physB(unsigned a) {
    return a ^ (((a >> 9) & 7u) << 4);
}

// Basis table mt[96][256] bf16 (detrend+window folded; R2-proven math):
//   col j=2i: w_n*cos(2pi(i+1)n/256); col j=2i+1: -w_n*sin(...);
//   col 0 adds +0.25 (exact detrend correction for k=1 real part).
//   Rows 90..95 zero (read by dummy cols of tile 5; outputs skipped).
__global__ void build_basis_kernel(unsigned short* __restrict__ mt) {
    int j = blockIdx.x, n = threadIdx.x;
    const float TH = 0.02454369260617026f;           // 2*pi/256
    float w = 0.5f - 0.5f * cosf((float)n * TH);     // periodic hann
    float v = 0.f;
    if (j < 90) {
        int k = (j >> 1) + 1;
        int m = (k * n) & 255;                       // exact periodic reduction
        float th = (float)m * TH;
        v = (j & 1) ? (-w * sinf(th)) : (w * cosf(th));
        if (j == 0) v += 0.25f;                      // fold detrend into k=1 re
    }
    mt[j * 256 + n] = (unsigned short)f2bf(v);
}

// Wave-private channels, REGISTER-DIETED to fit the allocator's 64-reg budget
// (R14: full k0 unroll hoisted 16 f32x4 loads -> 64-reg demand spike -> 202MB
// scratch spills at the compiler-chosen 64 cap -> 110us).
//  - #pragma unroll 1 on k0: only 2 f32x4 loads in flight (8 regs). Latency
//    covered by TLP (24 waves/CU) + L1 (rt working set 8KB: row r's k>=128
//    half == row r+1's k<128 half).
//  - address arrays gone: b0 + ct*8192 + k0*64 (disjoint bit ranges), XOR
//    LAST with swz=(col0&7)<<4  [j&7 == col0&7 since ct*16 = 0 mod 8].
//  - Census: acc24 + p6 + loads8 + a4 + b4 + misc10 ~= 56 < 64.
// Ledger: no MFMA guards (R3-R5), no breg hoist (R7-R11), B via ds_read,
// junk rows 59..63 via address clamp + square-sum mask (R14-proven).
__global__ __launch_bounds__(NTHR, 4)
void welch_main_kernel(const float* __restrict__ x,
                       const unsigned short* __restrict__ mt,
                       float* __restrict__ out) {
    __shared__ __align__(16) unsigned short mt_lds[96 * 256];  // 49152 B

    const int tid  = threadIdx.x;
    const int lane = tid & 63;
    const int w    = tid >> 6;

    // ---- stage mt (3072 x 16B = 6*512), physB-swizzled
    {
        const uint4* mt4 = reinterpret_cast<const uint4*>(mt);
        #pragma unroll
        for (int i = 0; i < 6; ++i) {
            int c = i * NTHR + tid;
            uint4 v = mt4[c];
            *reinterpret_cast<uint4*>((char*)mt_lds + physB((unsigned)c * 16u)) = v;
        }
    }
    __syncthreads();   // the only barrier in the kernel

    const int ch = blockIdx.x * 8 + w;
    const float* gx = x + (size_t)ch * T_LEN;
    const int col0 = lane & 15;
    const int q    = lane >> 4;

    const unsigned b0  = (unsigned)(col0 * 512 + q * 16);
    const unsigned swz = (unsigned)((col0 & 7) << 4);

    float p[6] = {0.f, 0.f, 0.f, 0.f, 0.f, 0.f};

    #pragma unroll
    for (int rt = 0; rt < 4; ++rt) {
        const int row     = rt * 16 + col0;
        const int row_eff = row > 58 ? 58 : row;        // clamp: junk rows
        const float* rowp = gx + row_eff * 128 + q * 8;

        f32x4 acc[6];
        #pragma unroll
        for (int ct = 0; ct < 6; ++ct) acc[ct] = (f32x4){0.f, 0.f, 0.f, 0.f};

        #pragma unroll 1
        for (int k0 = 0; k0 < 8; ++k0) {
            f32x4 x0 = *reinterpret_cast<const f32x4*>(rowp + k0 * 32);
            f32x4 x1 = *reinterpret_cast<const f32x4*>(rowp + k0 * 32 + 4);
            unsigned d0 = f2bf(x0[0]) | (f2bf(x0[1]) << 16);
            unsigned d1 = f2bf(x0[2]) | (f2bf(x0[3]) << 16);
            unsigned d2 = f2bf(x1[0]) | (f2bf(x1[1]) << 16);
            unsigned d3 = f2bf(x1[2]) | (f2bf(x1[3]) << 16);
            uint4 pk = {d0, d1, d2, d3};
            bf16x8 a = __builtin_bit_cast(bf16x8, pk);
            const unsigned koff = b0 + (unsigned)(k0 * 64);
            #pragma unroll
            for (int ct = 0; ct < 6; ++ct) {
                bf16x8 b = *reinterpret_cast<const bf16x8*>(
                    (char*)mt_lds + ((koff + (unsigned)(ct * 8192)) ^ swz));
                acc[ct] = __builtin_amdgcn_mfma_f32_16x16x32_bf16(a, b, acc[ct], 0, 0, 0);
            }
        }

        // square-sum fold; C/D layout: col=lane&15, row=rt*16 + q*4 + r.
        const int rowbase = rt * 16 + q * 4;
        #pragma unroll
        for (int ct = 0; ct < 6; ++ct) {
            float s = 0.f;
            #pragma unroll
            for (int r = 0; r < 4; ++r)
                if (rowbase + r < NSEG) s += acc[ct][r] * acc[ct][r];
            p[ct] += s;
        }
    }

    // ---- wave-local reduction + output (45 bins for this wave's channel)
    const float CNORM = 2.0f / (24576.0f * 59.0f);     // fs*sum(w^2) = 256*96
    #pragma unroll
    for (int ct = 0; ct < 6; ++ct) {
        float v = p[ct];
        v += __shfl_xor(v, 16);
        v += __shfl_xor(v, 32);    // col total (sum over all row-groups)
        v += __shfl_xor(v, 1);     // re^2 + im^2 (col pair)
        int bin = ct * 8 + (col0 >> 1);
        if (lane < 16 && (lane & 1) == 0 && bin < NBINS)
            out[(size_t)ch * NBINS + bin] = log1pf(v * CNORM);
    }
}

extern "C" void kernel_launch(void* const* d_in, const int* in_sizes, int n_in,
                              void* d_out, int out_size, void* d_ws, size_t ws_size,
                              hipStream_t stream) {
    const float* x = (const float*)d_in[0];
    float* out = (float*)d_out;
    unsigned short* mt = (unsigned short*)d_ws;   // 96*256*2 = 49152 B

    build_basis_kernel<<<96, 256, 0, stream>>>(mt);
    welch_main_kernel<<<NBLK, NTHR, 0, stream>>>(x, mt, out);
}